// Round 1
// baseline (865.236 us; speedup 1.0000x reference)
//
#include <hip/hip_runtime.h>
#include <hip/hip_bf16.h>
#include <math.h>

// MMCL PGD, restructured:
//   grad[b][r] = S*(1-KKd0[b][r]) + 2.1*z[r] + H[r] - H[b] - 1
// with H = KKd0 @ z (symmetric KKd0), rows b fully independent across the
// 300 FISTA iterations -> one workgroup per b, no grid sync.

__global__ __launch_bounds__(256) void mmcl_prep(const float* __restrict__ feat,
                                                 float* __restrict__ kkd0,
                                                 float* __restrict__ ksT,
                                                 float* __restrict__ out) {
    const int x = blockIdx.x;   // second index (column of KK / Ks)
    const int y = threadIdx.x;  // first index (row)
    __shared__ float sf[256];   // sf[0..127]=F0[x], sf[128..255]=F1[x]
    sf[y] = feat[x * 256 + y];
    __syncthreads();
    const float4* fy = (const float4*)(feat + y * 256);  // F0[y]
    const float4* s0 = (const float4*)(sf);
    const float4* s1 = (const float4*)(sf + 128);
    float d0 = 0.f, d1 = 0.f;
#pragma unroll
    for (int q = 0; q < 32; ++q) {
        float4 f = fy[q];
        float4 a = s0[q];
        float4 b = s1[q];
        d0 = fmaf(f.x, a.x, d0); d0 = fmaf(f.y, a.y, d0);
        d0 = fmaf(f.z, a.z, d0); d0 = fmaf(f.w, a.w, d0);
        d1 = fmaf(f.x, b.x, d1); d1 = fmaf(f.y, b.y, d1);
        d1 = fmaf(f.z, b.z, d1); d1 = fmaf(f.w, b.w, d1);
    }
    const float g = (float)(1.0 / 0.07);
    float kkv = expf(-g * (2.f - 2.f * d0));   // KK[y][x] (symmetric)
    float ksv = expf(-g * (2.f - 2.f * d1));   // Ks[y][x]
    kkd0[x * 256 + y] = (x == y) ? 0.f : kkv;  // zero diagonal
    ksT[x * 256 + y]  = ksv;                   // ksT[b][r] = Ks[r][b]
    if (x == 0 && y == 0) out[0] = 0.f;        // harness poisons d_out
}

__global__ __launch_bounds__(256, 1) void mmcl_fista(const float* __restrict__ kkd0,
                                                     const float* __restrict__ ksT,
                                                     const float* __restrict__ alpha_init,
                                                     float* __restrict__ out) {
    const int b = blockIdx.x;
    const int r = threadIdx.x;
    const int wave = r >> 6, lane = r & 63;

    __shared__ float zs[256];
    __shared__ float wsum[4];
    __shared__ float hbb_sh;
    __shared__ float red[4];

    // Column r of KKd0 == row r (symmetric): cache in registers.
    float kk[256];
    {
        const float4* kkrow = (const float4*)(kkd0 + r * 256);
#pragma unroll
        for (int q = 0; q < 64; ++q) {
            float4 v = kkrow[q];
            kk[4 * q + 0] = v.x; kk[4 * q + 1] = v.y;
            kk[4 * q + 2] = v.z; kk[4 * q + 3] = v.w;
        }
    }
    const float kkbr = kkd0[b * 256 + r];  // KKd0[b][r]

    // alpha0 = clip(relu(alpha_init)), scattered to full coords (diag = 0)
    float a;
    if (r == b) {
        a = 0.f;
    } else {
        int n = (r < b) ? r : (r - 1);
        float v = alpha_init[b * 255 + n];
        a = fminf(fmaxf(v, 0.f), 1.f);
    }
    float ap = a;
    float t = 1.f;

    for (int it = 0; it < 300; ++it) {
        float tn = (1.f + sqrtf(fmaf(4.f * t, t, 1.f))) * 0.5f;
        float beta = (t - 1.f) / tn;
        float z = fmaf(beta, a - ap, a);   // z[b][b] == 0 automatically

        zs[r] = z;
        // wave-level partial sum of z
        float ws = z;
#pragma unroll
        for (int off = 32; off > 0; off >>= 1) ws += __shfl_down(ws, off, 64);
        if (lane == 0) wsum[wave] = ws;
        __syncthreads();
        float S = (wsum[0] + wsum[1]) + (wsum[2] + wsum[3]);

        // H[r] = sum_{r'} zs[r'] * KKd0[r'][r]
        float h0 = 0.f, h1 = 0.f, h2 = 0.f, h3 = 0.f;
        const float4* z4 = (const float4*)zs;
#pragma unroll
        for (int q = 0; q < 64; ++q) {
            float4 zv = z4[q];
            h0 = fmaf(zv.x, kk[4 * q + 0], h0);
            h1 = fmaf(zv.y, kk[4 * q + 1], h1);
            h2 = fmaf(zv.z, kk[4 * q + 2], h2);
            h3 = fmaf(zv.w, kk[4 * q + 3], h3);
        }
        float H = (h0 + h1) + (h2 + h3);

        if (r == b) hbb_sh = H;
        __syncthreads();
        float Hb = hbb_sh;

        float grad = S * (1.f - kkbr) + 2.1f * z + (H - Hb) - 1.f;
        ap = a;
        float an = z - 0.001f * grad;
        an = fminf(fmaxf(an, 0.f), 1.f);
        a = (r == b) ? 0.f : an;
        t = tn;
    }

    // loss: sum_b sum_r a*Ks[r][b]  -  (1/256) sum_b (sum_r a)*Ks[b][b]
    a = fminf(fmaxf(a, 0.f), 1.f);
    const float ksd = ksT[b * 256 + b];
    float contrib = a * (ksT[b * 256 + r] - ksd * (1.f / 256.f));

    float s = contrib;
#pragma unroll
    for (int off = 32; off > 0; off >>= 1) s += __shfl_down(s, off, 64);
    if (lane == 0) red[wave] = s;
    __syncthreads();
    if (r == 0) {
        float tot = (red[0] + red[1]) + (red[2] + red[3]);
        atomicAdd(out, tot);
    }
}

extern "C" void kernel_launch(void* const* d_in, const int* in_sizes, int n_in,
                              void* d_out, int out_size, void* d_ws, size_t ws_size,
                              hipStream_t stream) {
    const float* feat = (const float*)d_in[0];        // (256, 2, 128) f32
    const float* alpha_init = (const float*)d_in[1];  // (256, 255, 1) f32
    float* out = (float*)d_out;                       // scalar f32

    float* kkd0 = (float*)d_ws;                       // 256*256 f32
    float* ksT  = kkd0 + 256 * 256;                   // 256*256 f32

    mmcl_prep<<<256, 256, 0, stream>>>(feat, kkd0, ksT, out);
    mmcl_fista<<<256, 256, 0, stream>>>(kkd0, ksT, alpha_init, out);
}